// Round 1
// baseline (532.389 us; speedup 1.0000x reference)
//
#include <hip/hip_runtime.h>
#include <math.h>

#define H 8
#define B 8
#define C 512
#define L 1024
#define D 64

// ---------------------------------------------------------------------------
// Grouped conv1d, k=3, reflect pad. One WG = (conv_id, b, h, 64-l tile).
// qh/kh written [BH, L, D]; vh written [BH, D, L] (transposed for PV reads).
// ---------------------------------------------------------------------------
__global__ __launch_bounds__(256) void conv_kernel(
    const float* __restrict__ q, const float* __restrict__ k,
    const float* __restrict__ wq, const float* __restrict__ wk,
    const float* __restrict__ wv,
    float* __restrict__ qh, float* __restrict__ kh, float* __restrict__ vh)
{
    int bx   = blockIdx.x;
    int tile = bx & 15;
    int h    = (bx >> 4) & 7;
    int b    = (bx >> 7) & 7;
    int conv = bx >> 10;                 // 0:q->qh  1:k->kh  2:k->vh

    const float* x   = (conv == 0) ? q  : k;
    const float* w   = (conv == 0) ? wq : (conv == 1) ? wk : wv;
    float*       out = (conv == 0) ? qh : (conv == 1) ? kh : vh;
    int mode = (conv == 2) ? 1 : 0;      // 1 -> [D,L] output layout

    __shared__ float xs[64 * 68];        // [j][p], p in 0..65, stride 68
    __shared__ float wt[192 * 68];       // [j*3+t][d], stride 68

    int l0  = tile * 64;
    int tid = threadIdx.x;

    // stage x tile (positions l0-1 .. l0+64, reflect at edges)
    const float* xb = x + (size_t)(b * C + h * 64) * L;
    for (int idx = tid; idx < 64 * 66; idx += 256) {
        int j = idx / 66;
        int p = idx - j * 66;
        int gl = l0 - 1 + p;
        if (gl < 0) gl = 1;              // reflect left: x[-1] -> x[1]
        if (gl >= L) gl = L - 2;         // reflect right: x[L] -> x[L-2]
        xs[j * 68 + p] = xb[j * L + gl];
    }
    // stage weights transposed: wt[j*3+t][d] = w[(h*64+d)*192 + j*3+t]
    const float* wb = w + (size_t)h * 64 * 192;
    for (int idx = tid; idx < 64 * 192; idx += 256) {
        int d = idx / 192;
        int r = idx - d * 192;
        wt[r * 68 + d] = wb[idx];
    }
    __syncthreads();

    int lt = tid >> 4;                   // l = 4*lt + a
    int dt = tid & 15;                   // d = 4*dt + bb

    float acc[4][4];
    #pragma unroll
    for (int a = 0; a < 4; a++)
        #pragma unroll
        for (int bb = 0; bb < 4; bb++) acc[a][bb] = 0.f;

    for (int j = 0; j < 64; j++) {
        const float* xr = &xs[j * 68 + 4 * lt];
        float xv[6];
        #pragma unroll
        for (int t = 0; t < 6; t++) xv[t] = xr[t];
        const float* wr = &wt[(j * 3) * 68 + 4 * dt];
        float4 w0 = *(const float4*)(wr);
        float4 w1 = *(const float4*)(wr + 68);
        float4 w2 = *(const float4*)(wr + 136);
        #pragma unroll
        for (int a = 0; a < 4; a++) {
            acc[a][0] += xv[a] * w0.x + xv[a + 1] * w1.x + xv[a + 2] * w2.x;
            acc[a][1] += xv[a] * w0.y + xv[a + 1] * w1.y + xv[a + 2] * w2.y;
            acc[a][2] += xv[a] * w0.z + xv[a + 1] * w1.z + xv[a + 2] * w2.z;
            acc[a][3] += xv[a] * w0.w + xv[a + 1] * w1.w + xv[a + 2] * w2.w;
        }
    }

    int bh = b * H + h;
    if (mode == 0) {                     // [L, D] rows
        float* ob = out + ((size_t)bh * L + l0) * 64;
        #pragma unroll
        for (int a = 0; a < 4; a++) {
            float4 v = make_float4(acc[a][0], acc[a][1], acc[a][2], acc[a][3]);
            *(float4*)(ob + (4 * lt + a) * 64 + 4 * dt) = v;
        }
    } else {                             // [D, L] rows
        float* ob = out + (size_t)bh * 64 * L + l0;
        #pragma unroll
        for (int bb = 0; bb < 4; bb++) {
            float4 v = make_float4(acc[0][bb], acc[1][bb], acc[2][bb], acc[3][bb]);
            *(float4*)(ob + (4 * dt + bb) * L + 4 * lt) = v;
        }
    }
}

// ---------------------------------------------------------------------------
// Causal flash attention, fp32. One WG = (b, h, 64-row q tile).
// qh/kh: [BH, L, D]; vh: [BH, D, L]. Output o: [B, L, C] (c = h*64+d).
// ---------------------------------------------------------------------------
__global__ __launch_bounds__(256) void flash_kernel(
    const float* __restrict__ qh, const float* __restrict__ kh,
    const float* __restrict__ vh, float* __restrict__ o)
{
    int bx = blockIdx.x;
    int qt = bx & 15;
    int bh = bx >> 4;                    // 0..63
    int h  = bh & 7;
    int b  = bh >> 3;

    __shared__ float Qs[64 * 68];        // [l][d]
    __shared__ float Ks[64 * 68];        // [m][d]
    __shared__ float Vs[64 * 68];        // [d][m]  (V^T tile)
    __shared__ float Ps[64 * 68];        // [l][m]

    int tid = threadIdx.x;
    int lt = tid >> 4, mt = tid & 15;    // rows l=4lt+r; cols m(or d)=mt+16c

    const float scale = 0.35355339059327373f;  // 1/sqrt(H)
    const float* Qg = qh + ((size_t)bh * L + qt * 64) * 64;
    for (int i = tid; i < 1024; i += 256) {
        int row = i >> 4, c4 = i & 15;
        float4 v = ((const float4*)Qg)[row * 16 + c4];
        v.x *= scale; v.y *= scale; v.z *= scale; v.w *= scale;
        *(float4*)&Qs[row * 68 + c4 * 4] = v;
    }

    float Oa[4][4], mi[4], li[4];
    #pragma unroll
    for (int r = 0; r < 4; r++) {
        mi[r] = -INFINITY; li[r] = 0.f;
        #pragma unroll
        for (int c = 0; c < 4; c++) Oa[r][c] = 0.f;
    }

    for (int kt = 0; kt <= qt; kt++) {
        __syncthreads();                 // previous PV done before overwrite
        const float* Kg = kh + ((size_t)bh * L + kt * 64) * 64;
        const float* Vg = vh + (size_t)bh * 64 * L + kt * 64;
        for (int i = tid; i < 1024; i += 256) {
            int row = i >> 4, c4 = i & 15;
            *(float4*)&Ks[row * 68 + c4 * 4] = ((const float4*)Kg)[row * 16 + c4];
            *(float4*)&Vs[row * 68 + c4 * 4] = *(const float4*)(Vg + row * L + c4 * 4);
        }
        __syncthreads();

        // S = Q K^T (scaled), 4x4 micro-tile per thread
        float s[4][4];
        #pragma unroll
        for (int r = 0; r < 4; r++)
            #pragma unroll
            for (int c = 0; c < 4; c++) s[r][c] = 0.f;
        for (int d0 = 0; d0 < 64; d0 += 4) {
            float4 qv[4], kv[4];
            #pragma unroll
            for (int r = 0; r < 4; r++)
                qv[r] = *(const float4*)&Qs[(4 * lt + r) * 68 + d0];
            #pragma unroll
            for (int c = 0; c < 4; c++)
                kv[c] = *(const float4*)&Ks[(mt + 16 * c) * 68 + d0];
            #pragma unroll
            for (int r = 0; r < 4; r++)
                #pragma unroll
                for (int c = 0; c < 4; c++)
                    s[r][c] += qv[r].x * kv[c].x + qv[r].y * kv[c].y
                             + qv[r].z * kv[c].z + qv[r].w * kv[c].w;
        }

        if (kt == qt) {                  // causal mask on diagonal tile
            #pragma unroll
            for (int r = 0; r < 4; r++) {
                int lg = 4 * lt + r;
                #pragma unroll
                for (int c = 0; c < 4; c++)
                    if (mt + 16 * c > lg) s[r][c] = -INFINITY;
            }
        }

        // online softmax: reduce across the 16 lanes sharing each row
        float rm[4];
        #pragma unroll
        for (int r = 0; r < 4; r++)
            rm[r] = fmaxf(fmaxf(s[r][0], s[r][1]), fmaxf(s[r][2], s[r][3]));
        #pragma unroll
        for (int off = 1; off < 16; off <<= 1)
            #pragma unroll
            for (int r = 0; r < 4; r++)
                rm[r] = fmaxf(rm[r], __shfl_xor(rm[r], off, 64));

        float alpha[4], rs[4];
        #pragma unroll
        for (int r = 0; r < 4; r++) {
            float mnew = fmaxf(mi[r], rm[r]);
            alpha[r] = __expf(mi[r] - mnew);
            mi[r] = mnew;
            float ls = 0.f;
            #pragma unroll
            for (int c = 0; c < 4; c++) {
                float p = __expf(s[r][c] - mnew);   // masked: exp(-inf)=0
                s[r][c] = p;
                ls += p;
            }
            rs[r] = ls;
        }
        #pragma unroll
        for (int off = 1; off < 16; off <<= 1)
            #pragma unroll
            for (int r = 0; r < 4; r++)
                rs[r] += __shfl_xor(rs[r], off, 64);

        #pragma unroll
        for (int r = 0; r < 4; r++) {
            li[r] = li[r] * alpha[r] + rs[r];
            #pragma unroll
            for (int c = 0; c < 4; c++) Oa[r][c] *= alpha[r];
            #pragma unroll
            for (int c = 0; c < 4; c++)
                Ps[(4 * lt + r) * 68 + mt + 16 * c] = s[r][c];
        }
        __syncthreads();                 // Ps visible to all lanes

        // O += P V^T-tile : O[l][d=mt+16c] += sum_m P[l][m] * Vs[d][m]
        for (int m0 = 0; m0 < 64; m0 += 4) {
            float4 pv[4], vv[4];
            #pragma unroll
            for (int r = 0; r < 4; r++)
                pv[r] = *(const float4*)&Ps[(4 * lt + r) * 68 + m0];
            #pragma unroll
            for (int c = 0; c < 4; c++)
                vv[c] = *(const float4*)&Vs[(mt + 16 * c) * 68 + m0];
            #pragma unroll
            for (int r = 0; r < 4; r++)
                #pragma unroll
                for (int c = 0; c < 4; c++)
                    Oa[r][c] += pv[r].x * vv[c].x + pv[r].y * vv[c].y
                              + pv[r].z * vv[c].z + pv[r].w * vv[c].w;
        }
    }

    // epilogue: o[b][l][h*64 + d]
    #pragma unroll
    for (int r = 0; r < 4; r++) {
        float inv = 1.f / li[r];
        int l = qt * 64 + 4 * lt + r;
        float* ob = o + ((size_t)b * L + l) * C + h * 64;
        #pragma unroll
        for (int c = 0; c < 4; c++)
            ob[mt + 16 * c] = Oa[r][c] * inv;
    }
}

// ---------------------------------------------------------------------------
// Residual + LayerNorm over channels; transposed write y[B,C,L].
// One WG = (b, 16-l tile).
// ---------------------------------------------------------------------------
__global__ __launch_bounds__(256) void ln_kernel(
    const float* __restrict__ o, const float* __restrict__ q,
    const float* __restrict__ gamma, const float* __restrict__ beta,
    float* __restrict__ y)
{
    int bx = blockIdx.x;
    int tile = bx & 63;
    int b = bx >> 6;
    int l0 = tile * 16;
    int tid = threadIdx.x;

    __shared__ float xt[16 * 516];       // [lq][c], stride 516 (16B aligned)
    __shared__ float mu_s[16], rs_s[16];

    // phase 1: x = o[b][l0+lq][:]
    const float4* og = (const float4*)(o + ((size_t)b * L + l0) * C);
    for (int i = tid; i < 16 * 128; i += 256) {
        int l = i >> 7, c4 = i & 127;
        *(float4*)&xt[l * 516 + c4 * 4] = og[l * 128 + c4];
    }
    __syncthreads();
    // phase 2: x += q[b][c][l0+lq]  (residual)
    const float* qb = q + (size_t)b * C * L + l0;
    for (int i = tid; i < 16 * 512; i += 256) {
        int c = i >> 4, lq = i & 15;
        xt[lq * 516 + c] += qb[c * L + lq];
    }
    __syncthreads();
    // phase 3: mean/var per row
    {
        int l = tid >> 4, sub = tid & 15;
        float s = 0.f, ss = 0.f;
        for (int j = 0; j < 32; j++) {
            float v = xt[l * 516 + sub + 16 * j];
            s += v; ss += v * v;
        }
        #pragma unroll
        for (int off = 1; off < 16; off <<= 1) {
            s  += __shfl_xor(s, off, 64);
            ss += __shfl_xor(ss, off, 64);
        }
        if (sub == 0) {
            float mean = s * (1.f / 512.f);
            float var  = ss * (1.f / 512.f) - mean * mean;
            mu_s[l] = mean;
            rs_s[l] = rsqrtf(var + 1e-5f);
        }
    }
    __syncthreads();
    // phase 4: y[b][c][l0+lq] = (x - mu) * rstd * gamma + beta
    float* yb = y + (size_t)b * C * L + l0;
    for (int i = tid; i < 16 * 512; i += 256) {
        int c = i >> 4, lq = i & 15;
        float v = (xt[lq * 516 + c] - mu_s[lq]) * rs_s[lq] * gamma[c] + beta[c];
        yb[c * L + lq] = v;
    }
}

// ---------------------------------------------------------------------------
extern "C" void kernel_launch(void* const* d_in, const int* in_sizes, int n_in,
                              void* d_out, int out_size, void* d_ws, size_t ws_size,
                              hipStream_t stream)
{
    const float* q     = (const float*)d_in[0];
    const float* k     = (const float*)d_in[1];
    // d_in[2] = mask (causal triu) — implemented analytically, not read
    const float* wq    = (const float*)d_in[3];
    const float* wk    = (const float*)d_in[4];
    const float* wv    = (const float*)d_in[5];
    const float* gamma = (const float*)d_in[6];
    const float* beta  = (const float*)d_in[7];
    float* y  = (float*)d_out;

    float* ws = (float*)d_ws;
    const size_t N = (size_t)B * H * L * D;      // 4,194,304
    float* qh = ws;                              // [BH, L, D]
    float* kh = ws + N;                          // [BH, L, D]
    float* vh = ws + 2 * N;                      // [BH, D, L]
    float* o  = ws + 3 * N;                      // [B, L, C]

    conv_kernel<<<3 * B * H * (L / 64), 256, 0, stream>>>(q, k, wq, wk, wv, qh, kh, vh);
    flash_kernel<<<B * H * (L / 64), 256, 0, stream>>>(qh, kh, vh, o);
    ln_kernel<<<B * (L / 16), 256, 0, stream>>>(o, q, gamma, beta, y);
}

// Round 2
// 235.128 us; speedup vs baseline: 2.2643x; 2.2643x over previous
//
#include <hip/hip_runtime.h>
#include <math.h>

#define H 8
#define B 8
#define C 512
#define L 1024
#define D 64
#define LDK 72   // bf16 LDS row stride: 144 B = 16B-aligned, frag reads 8 words/bank

typedef __attribute__((ext_vector_type(4))) float f32x4;
typedef __attribute__((ext_vector_type(8))) short bf16x8;

static __device__ __forceinline__ short f2bf(float x) {
    union { float f; unsigned u; } v; v.f = x;
    unsigned r = v.u + 0x7FFFu + ((v.u >> 16) & 1u);   // RNE
    return (short)(r >> 16);
}
static __device__ __forceinline__ int pack2(short a, short b) {
    return (int)((unsigned short)a | ((unsigned)(unsigned short)b << 16));
}

// ---------------------------------------------------------------------------
// Grouped conv1d, k=3, reflect pad. One WG = (conv_id, b, h, 64-l tile).
// Outputs bf16: qh/kh [BH, L, D]; vh [BH, D, L] (transposed for PV B-frags).
// ---------------------------------------------------------------------------
__global__ __launch_bounds__(256) void conv_kernel(
    const float* __restrict__ q, const float* __restrict__ k,
    const float* __restrict__ wq, const float* __restrict__ wk,
    const float* __restrict__ wv,
    short* __restrict__ qh, short* __restrict__ kh, short* __restrict__ vh)
{
    int bx   = blockIdx.x;
    int tile = bx & 15;
    int h    = (bx >> 4) & 7;
    int b    = (bx >> 7) & 7;
    int conv = bx >> 10;                 // 0:q->qh  1:k->kh  2:k->vh

    const float* x   = (conv == 0) ? q  : k;
    const float* w   = (conv == 0) ? wq : (conv == 1) ? wk : wv;
    short*       out = (conv == 0) ? qh : (conv == 1) ? kh : vh;
    int mode = (conv == 2) ? 1 : 0;      // 1 -> [D,L] output layout

    __shared__ float xs[64 * 68];        // [j][p], p in 0..65, stride 68
    __shared__ float wt[192 * 68];       // [j*3+t][d], stride 68

    int l0  = tile * 64;
    int tid = threadIdx.x;

    const float* xb = x + (size_t)(b * C + h * 64) * L;
    for (int idx = tid; idx < 64 * 66; idx += 256) {
        int j = idx / 66;
        int p = idx - j * 66;
        int gl = l0 - 1 + p;
        if (gl < 0) gl = 1;              // reflect left
        if (gl >= L) gl = L - 2;         // reflect right
        xs[j * 68 + p] = xb[j * L + gl];
    }
    const float* wb = w + (size_t)h * 64 * 192;
    for (int idx = tid; idx < 64 * 192; idx += 256) {
        int d = idx / 192;
        int r = idx - d * 192;
        wt[r * 68 + d] = wb[idx];
    }
    __syncthreads();

    int lt = tid >> 4;                   // l = 4*lt + a
    int dt = tid & 15;                   // d = 4*dt + bb

    float acc[4][4];
    #pragma unroll
    for (int a = 0; a < 4; a++)
        #pragma unroll
        for (int bb = 0; bb < 4; bb++) acc[a][bb] = 0.f;

    for (int j = 0; j < 64; j++) {
        const float* xr = &xs[j * 68 + 4 * lt];
        float xv[6];
        #pragma unroll
        for (int t = 0; t < 6; t++) xv[t] = xr[t];
        const float* wr = &wt[(j * 3) * 68 + 4 * dt];
        float4 w0 = *(const float4*)(wr);
        float4 w1 = *(const float4*)(wr + 68);
        float4 w2 = *(const float4*)(wr + 136);
        #pragma unroll
        for (int a = 0; a < 4; a++) {
            acc[a][0] += xv[a] * w0.x + xv[a + 1] * w1.x + xv[a + 2] * w2.x;
            acc[a][1] += xv[a] * w0.y + xv[a + 1] * w1.y + xv[a + 2] * w2.y;
            acc[a][2] += xv[a] * w0.z + xv[a + 1] * w1.z + xv[a + 2] * w2.z;
            acc[a][3] += xv[a] * w0.w + xv[a + 1] * w1.w + xv[a + 2] * w2.w;
        }
    }

    int bh = b * H + h;
    if (mode == 0) {                     // [L, D] rows, bf16
        short* ob = out + ((size_t)bh * L + l0) * 64;
        #pragma unroll
        for (int a = 0; a < 4; a++) {
            int2 v;
            v.x = pack2(f2bf(acc[a][0]), f2bf(acc[a][1]));
            v.y = pack2(f2bf(acc[a][2]), f2bf(acc[a][3]));
            *(int2*)&ob[(4 * lt + a) * 64 + 4 * dt] = v;
        }
    } else {                             // [D, L] rows, bf16
        short* ob = out + (size_t)bh * 64 * L + l0;
        #pragma unroll
        for (int bb = 0; bb < 4; bb++) {
            int2 v;
            v.x = pack2(f2bf(acc[0][bb]), f2bf(acc[1][bb]));
            v.y = pack2(f2bf(acc[2][bb]), f2bf(acc[3][bb]));
            *(int2*)&ob[(4 * dt + bb) * L + 4 * lt] = v;
        }
    }
}

// ---------------------------------------------------------------------------
// Causal flash attention, bf16 MFMA. One WG = (b, h, 64-row q tile);
// wave w owns q rows [w*16, w*16+16). qh/kh: [BH,L,D] bf16; vh: [BH,D,L] bf16.
// S/O in MFMA C-layout (col=lane&15, row=quad*4+reg); P round-trips LDS
// (per-wave region -> no barrier) to reach A-layout (m=lane&15, k=quad*8+j).
// ---------------------------------------------------------------------------
__global__ __launch_bounds__(256, 4) void flash_kernel(
    const short* __restrict__ qh, const short* __restrict__ kh,
    const short* __restrict__ vh, float* __restrict__ o)
{
    int bx = blockIdx.x;
    int bh = bx & 63;
    int qt = 15 - (bx >> 6);             // heavy tiles dispatch first
    int h  = bh & 7, b = bh >> 3;

    __shared__ short Qs[64 * LDK];       // [l][d]
    __shared__ short Ks[64 * LDK];       // [key][d]
    __shared__ short Vt[64 * LDK];       // [d][key]
    __shared__ short Ps[64 * LDK];       // [l][key], per-wave 16-row slices

    int tid  = threadIdx.x;
    int wave = tid >> 6, lane = tid & 63;
    int n    = lane & 15, quad = lane >> 4;

    // stage Q tile (64x64 bf16, 8KB)
    const short* Qg = qh + ((size_t)bh * L + qt * 64) * 64;
    for (int i = tid; i < 512; i += 256) {
        int row = i >> 3, ch = i & 7;
        *(int4*)&Qs[row * LDK + ch * 8] = ((const int4*)Qg)[i];
    }
    __syncthreads();
    bf16x8 qa0 = *(const bf16x8*)&Qs[(wave * 16 + n) * LDK + quad * 8];
    bf16x8 qa1 = *(const bf16x8*)&Qs[(wave * 16 + n) * LDK + 32 + quad * 8];

    f32x4 O0 = {0.f,0.f,0.f,0.f}, O1 = O0, O2 = O0, O3 = O0;
    float mi[4], li[4];
    #pragma unroll
    for (int r = 0; r < 4; r++) { mi[r] = -INFINITY; li[r] = 0.f; }

    const float scale = 0.35355339059327373f;   // 1/sqrt(H)

    for (int kt = 0; kt <= qt; kt++) {
        __syncthreads();                 // prior tile's frag reads done
        const short* Kg = kh + ((size_t)bh * L + kt * 64) * 64;
        const short* Vg = vh + (size_t)bh * 64 * L + kt * 64;
        for (int i = tid; i < 512; i += 256) {
            int row = i >> 3, ch = i & 7;
            *(int4*)&Ks[row * LDK + ch * 8] = ((const int4*)Kg)[i];
            *(int4*)&Vt[row * LDK + ch * 8] = *(const int4*)(Vg + row * (size_t)L + ch * 8);
        }
        __syncthreads();

        // S = Q K^T : A=Q[l][d], B=K^T[d][key] read from Ks[key][d]
        f32x4 s[4];
        #pragma unroll
        for (int bk = 0; bk < 4; bk++) {
            bf16x8 kb0 = *(const bf16x8*)&Ks[(bk * 16 + n) * LDK + quad * 8];
            bf16x8 kb1 = *(const bf16x8*)&Ks[(bk * 16 + n) * LDK + 32 + quad * 8];
            f32x4 acc = {0.f,0.f,0.f,0.f};
            acc = __builtin_amdgcn_mfma_f32_16x16x32_bf16(qa0, kb0, acc, 0, 0, 0);
            acc = __builtin_amdgcn_mfma_f32_16x16x32_bf16(qa1, kb1, acc, 0, 0, 0);
            s[bk] = acc;
        }

        #pragma unroll
        for (int bk = 0; bk < 4; bk++)
            #pragma unroll
            for (int r = 0; r < 4; r++) s[bk][r] *= scale;

        if (kt == qt) {                  // causal mask on diagonal tile
            #pragma unroll
            for (int bk = 0; bk < 4; bk++)
                #pragma unroll
                for (int r = 0; r < 4; r++)
                    if (bk * 16 + n > wave * 16 + quad * 4 + r)
                        s[bk][r] = -INFINITY;
        }

        // online softmax (rows live on 16 lanes of each quad group)
        float rmax[4], rsum[4], alpha[4];
        #pragma unroll
        for (int r = 0; r < 4; r++)
            rmax[r] = fmaxf(fmaxf(s[0][r], s[1][r]), fmaxf(s[2][r], s[3][r]));
        #pragma unroll
        for (int off = 1; off < 16; off <<= 1)
            #pragma unroll
            for (int r = 0; r < 4; r++)
                rmax[r] = fmaxf(rmax[r], __shfl_xor(rmax[r], off, 64));

        #pragma unroll
        for (int r = 0; r < 4; r++) {
            float mnew = fmaxf(mi[r], rmax[r]);
            alpha[r] = __expf(mi[r] - mnew);
            mi[r] = mnew;
            float ls = 0.f;
            #pragma unroll
            for (int bk = 0; bk < 4; bk++) {
                float p = __expf(s[bk][r] - mnew);   // masked: exp(-inf)=0
                s[bk][r] = p;
                ls += p;
            }
            rsum[r] = ls;
        }
        #pragma unroll
        for (int off = 1; off < 16; off <<= 1)
            #pragma unroll
            for (int r = 0; r < 4; r++)
                rsum[r] += __shfl_xor(rsum[r], off, 64);

        #pragma unroll
        for (int r = 0; r < 4; r++) {
            li[r] = li[r] * alpha[r] + rsum[r];
            O0[r] *= alpha[r]; O1[r] *= alpha[r];
            O2[r] *= alpha[r]; O3[r] *= alpha[r];
        }

        // P (C-layout) -> LDS -> A-layout. Per-wave rows: no barrier needed.
        #pragma unroll
        for (int bk = 0; bk < 4; bk++)
            #pragma unroll
            for (int r = 0; r < 4; r++)
                Ps[(wave * 16 + quad * 4 + r) * LDK + bk * 16 + n] = f2bf(s[bk][r]);

        bf16x8 pa0 = *(const bf16x8*)&Ps[(wave * 16 + n) * LDK + quad * 8];
        bf16x8 pa1 = *(const bf16x8*)&Ps[(wave * 16 + n) * LDK + 32 + quad * 8];

        // O += P V : B=V[key][d] read from Vt[d][key]
        {
            bf16x8 v0, v1;
            v0 = *(const bf16x8*)&Vt[(0 * 16 + n) * LDK + quad * 8];
            v1 = *(const bf16x8*)&Vt[(0 * 16 + n) * LDK + 32 + quad * 8];
            O0 = __builtin_amdgcn_mfma_f32_16x16x32_bf16(pa0, v0, O0, 0, 0, 0);
            O0 = __builtin_amdgcn_mfma_f32_16x16x32_bf16(pa1, v1, O0, 0, 0, 0);
            v0 = *(const bf16x8*)&Vt[(1 * 16 + n) * LDK + quad * 8];
            v1 = *(const bf16x8*)&Vt[(1 * 16 + n) * LDK + 32 + quad * 8];
            O1 = __builtin_amdgcn_mfma_f32_16x16x32_bf16(pa0, v0, O1, 0, 0, 0);
            O1 = __builtin_amdgcn_mfma_f32_16x16x32_bf16(pa1, v1, O1, 0, 0, 0);
            v0 = *(const bf16x8*)&Vt[(2 * 16 + n) * LDK + quad * 8];
            v1 = *(const bf16x8*)&Vt[(2 * 16 + n) * LDK + 32 + quad * 8];
            O2 = __builtin_amdgcn_mfma_f32_16x16x32_bf16(pa0, v0, O2, 0, 0, 0);
            O2 = __builtin_amdgcn_mfma_f32_16x16x32_bf16(pa1, v1, O2, 0, 0, 0);
            v0 = *(const bf16x8*)&Vt[(3 * 16 + n) * LDK + quad * 8];
            v1 = *(const bf16x8*)&Vt[(3 * 16 + n) * LDK + 32 + quad * 8];
            O3 = __builtin_amdgcn_mfma_f32_16x16x32_bf16(pa0, v0, O3, 0, 0, 0);
            O3 = __builtin_amdgcn_mfma_f32_16x16x32_bf16(pa1, v1, O3, 0, 0, 0);
        }
    }

    // epilogue: o[b][l][h*64 + d], C-layout rows quad*4+r
    #pragma unroll
    for (int r = 0; r < 4; r++) {
        float inv = 1.f / li[r];
        int lg = qt * 64 + wave * 16 + quad * 4 + r;
        float* ob = o + ((size_t)b * L + lg) * C + h * 64;
        ob[n]      = O0[r] * inv;
        ob[16 + n] = O1[r] * inv;
        ob[32 + n] = O2[r] * inv;
        ob[48 + n] = O3[r] * inv;
    }
}

// ---------------------------------------------------------------------------
// Residual + LayerNorm over channels; transposed write y[B,C,L].
// ---------------------------------------------------------------------------
__global__ __launch_bounds__(256) void ln_kernel(
    const float* __restrict__ o, const float* __restrict__ q,
    const float* __restrict__ gamma, const float* __restrict__ beta,
    float* __restrict__ y)
{
    int bx = blockIdx.x;
    int tile = bx & 63;
    int b = bx >> 6;
    int l0 = tile * 16;
    int tid = threadIdx.x;

    __shared__ float xt[16 * 516];
    __shared__ float mu_s[16], rs_s[16];

    const float4* og = (const float4*)(o + ((size_t)b * L + l0) * C);
    for (int i = tid; i < 16 * 128; i += 256) {
        int l = i >> 7, c4 = i & 127;
        *(float4*)&xt[l * 516 + c4 * 4] = og[l * 128 + c4];
    }
    __syncthreads();
    const float* qb = q + (size_t)b * C * L + l0;
    for (int i = tid; i < 16 * 512; i += 256) {
        int c = i >> 4, lq = i & 15;
        xt[lq * 516 + c] += qb[c * L + lq];
    }
    __syncthreads();
    {
        int l = tid >> 4, sub = tid & 15;
        float s = 0.f, ss = 0.f;
        for (int j = 0; j < 32; j++) {
            float v = xt[l * 516 + sub + 16 * j];
            s += v; ss += v * v;
        }
        #pragma unroll
        for (int off = 1; off < 16; off <<= 1) {
            s  += __shfl_xor(s, off, 64);
            ss += __shfl_xor(ss, off, 64);
        }
        if (sub == 0) {
            float mean = s * (1.f / 512.f);
            float var  = ss * (1.f / 512.f) - mean * mean;
            mu_s[l] = mean;
            rs_s[l] = rsqrtf(var + 1e-5f);
        }
    }
    __syncthreads();
    float* yb = y + (size_t)b * C * L + l0;
    for (int i = tid; i < 16 * 512; i += 256) {
        int c = i >> 4, lq = i & 15;
        float v = (xt[lq * 516 + c] - mu_s[lq]) * rs_s[lq] * gamma[c] + beta[c];
        yb[c * L + lq] = v;
    }
}

// ---------------------------------------------------------------------------
extern "C" void kernel_launch(void* const* d_in, const int* in_sizes, int n_in,
                              void* d_out, int out_size, void* d_ws, size_t ws_size,
                              hipStream_t stream)
{
    const float* q     = (const float*)d_in[0];
    const float* k     = (const float*)d_in[1];
    // d_in[2] = mask — analytic
    const float* wq    = (const float*)d_in[3];
    const float* wk    = (const float*)d_in[4];
    const float* wv    = (const float*)d_in[5];
    const float* gamma = (const float*)d_in[6];
    const float* beta  = (const float*)d_in[7];
    float* y = (float*)d_out;

    const size_t N = (size_t)B * H * L * D;      // 4,194,304
    short* qh = (short*)d_ws;                    // [BH, L, D] bf16
    short* kh = qh + N;                          // [BH, L, D] bf16
    short* vh = kh + N;                          // [BH, D, L] bf16
    float* o  = (float*)(vh + N);                // [B, L, C] fp32

    conv_kernel<<<3 * B * H * (L / 64), 256, 0, stream>>>(q, k, wq, wk, wv, qh, kh, vh);
    flash_kernel<<<B * H * (L / 64), 256, 0, stream>>>(qh, kh, vh, o);
    ln_kernel<<<B * (L / 16), 256, 0, stream>>>(o, q, gamma, beta, y);
}

// Round 3
// 157.248 us; speedup vs baseline: 3.3857x; 1.4953x over previous
//
#include <hip/hip_runtime.h>
#include <math.h>

#define H 8
#define B 8
#define C 512
#define L 1024
#define D 64
#define LDK 72   // bf16 LDS row stride: 144 B = 16B-aligned, frag reads 8 words/bank

typedef __attribute__((ext_vector_type(4))) float f32x4;
typedef __attribute__((ext_vector_type(8))) short bf16x8;

static __device__ __forceinline__ short f2bf(float x) {
    union { float f; unsigned u; } v; v.f = x;
    unsigned r = v.u + 0x7FFFu + ((v.u >> 16) & 1u);   // RNE
    return (short)(r >> 16);
}
static __device__ __forceinline__ int pack2(short a, short b) {
    return (int)((unsigned short)a | ((unsigned)(unsigned short)b << 16));
}

// ---------------------------------------------------------------------------
// Weight prep: w[conv][(h*64+d)*192 + j*3 + t] fp32 ->
// wtg bf16 in A-fragment order: [((conv*8+h)*3+t)*2+khalf][d][quad][jj]
// so a conv wave can load its A-frag as one coalesced int4 per lane.
// ---------------------------------------------------------------------------
__global__ __launch_bounds__(256) void wprep_kernel(
    const float* __restrict__ wq, const float* __restrict__ wk,
    const float* __restrict__ wv, short* __restrict__ wtg)
{
    int idx = blockIdx.x * 256 + threadIdx.x;       // < 294912
    int jj    = idx & 7;
    int quad  = (idx >> 3) & 3;
    int d     = (idx >> 5) & 63;
    int r     = idx >> 11;
    int khalf = r & 1;  r >>= 1;
    int t     = r % 3;  r /= 3;
    int h     = r & 7;
    int conv  = r >> 3;
    const float* w = (conv == 0) ? wq : (conv == 1) ? wk : wv;
    int j_in = khalf * 32 + quad * 8 + jj;
    wtg[idx] = f2bf(w[(h * 64 + d) * 192 + j_in * 3 + t]);
}

// ---------------------------------------------------------------------------
// Grouped conv1d as bf16 MFMA. out[d][l] = sum_t W_t[d][:] . X[:][l-1+t]
// WG = (src, b, h, 64-l tile); src=0: q->qh, src=1: k->kh AND k->vh (shared
// staged X and B-frags). X^T staged in LDS [pos][j]; t-shift = row offset.
// Wave bd computes d rows [16bd,16bd+16) for all 4 l-blocks.
// ---------------------------------------------------------------------------
__global__ __launch_bounds__(256) void conv_kernel(
    const float* __restrict__ q, const float* __restrict__ k,
    const short* __restrict__ wtg,
    short* __restrict__ qh, short* __restrict__ kh, short* __restrict__ vh)
{
    int bx   = blockIdx.x;
    int tile = bx & 15;
    int h    = (bx >> 4) & 7;
    int b    = (bx >> 7) & 7;
    int src  = bx >> 10;                 // 0: q->qh   1: k->kh+vh

    __shared__ short xT[66 * LDK];       // [p][j], p = l0-1 .. l0+64

    int l0  = tile * 64;
    int tid = threadIdx.x;
    int wave = tid >> 6, lane = tid & 63;
    int n = lane & 15, quad = lane >> 4;

    const float* x  = src ? k : q;
    const float* xb = x + (size_t)(b * C + h * 64) * L + l0;

    // A-frags direct from pre-swizzled global (no LDS round-trip)
    int c0 = src ? 1 : 0;
    const short* wb0 = wtg + (size_t)((c0 * 8 + h) * 3 * 2) * 2048;
    bf16x8 wf[3][2], wf2[3][2];
    #pragma unroll
    for (int t = 0; t < 3; t++)
        #pragma unroll
        for (int kk = 0; kk < 2; kk++)
            wf[t][kk] = *(const bf16x8*)(wb0 + (t * 2 + kk) * 2048
                                         + (wave * 16 + n) * 32 + quad * 8);
    if (src) {
        const short* wb1 = wtg + (size_t)((2 * 8 + h) * 3 * 2) * 2048;
        #pragma unroll
        for (int t = 0; t < 3; t++)
            #pragma unroll
            for (int kk = 0; kk < 2; kk++)
                wf2[t][kk] = *(const bf16x8*)(wb1 + (t * 2 + kk) * 2048
                                              + (wave * 16 + n) * 32 + quad * 8);
    }

    // stage X^T (fp32 -> bf16 transpose): interior p=1..64 via float4
    {
        int j = tid >> 2;
        #pragma unroll
        for (int s = 0; s < 4; s++) {
            int i = (tid & 3) + s * 4;           // 0..15
            float4 v = *(const float4*)(xb + j * L + i * 4);
            int p = 1 + i * 4;
            xT[(p + 0) * LDK + j] = f2bf(v.x);
            xT[(p + 1) * LDK + j] = f2bf(v.y);
            xT[(p + 2) * LDK + j] = f2bf(v.z);
            xT[(p + 3) * LDK + j] = f2bf(v.w);
        }
        if (tid < 64) {                          // p=0 (reflect left)
            int gl = (l0 == 0) ? 1 : (l0 - 1);
            xT[0 * LDK + tid] = f2bf(x[(size_t)(b * C + h * 64 + tid) * L + gl]);
        } else if (tid < 128) {                  // p=65 (reflect right)
            int j2 = tid - 64;
            int gl = (l0 + 64 >= L) ? (L - 2) : (l0 + 64);
            xT[65 * LDK + j2] = f2bf(x[(size_t)(b * C + h * 64 + j2) * L + gl]);
        }
    }
    __syncthreads();

    f32x4 acc[4], acc2[4];
    #pragma unroll
    for (int bl = 0; bl < 4; bl++) {
        acc[bl]  = (f32x4){0.f, 0.f, 0.f, 0.f};
        acc2[bl] = (f32x4){0.f, 0.f, 0.f, 0.f};
    }

    #pragma unroll
    for (int bl = 0; bl < 4; bl++) {
        #pragma unroll
        for (int t = 0; t < 3; t++) {
            #pragma unroll
            for (int kk = 0; kk < 2; kk++) {
                bf16x8 bf = *(const bf16x8*)&xT[(bl * 16 + n + t) * LDK
                                                + kk * 32 + quad * 8];
                acc[bl] = __builtin_amdgcn_mfma_f32_16x16x32_bf16(
                    wf[t][kk], bf, acc[bl], 0, 0, 0);
                if (src)
                    acc2[bl] = __builtin_amdgcn_mfma_f32_16x16x32_bf16(
                        wf2[t][kk], bf, acc2[bl], 0, 0, 0);
            }
        }
    }

    // C layout: row(d) = quad*4+r, col(l) = n
    int bhh = b * H + h;
    short* o1 = src ? kh : qh;
    {
        short* ob = o1 + ((size_t)bhh * L + l0) * 64;
        #pragma unroll
        for (int bl = 0; bl < 4; bl++) {
            int lg = bl * 16 + n;
            int2 v;
            v.x = pack2(f2bf(acc[bl][0]), f2bf(acc[bl][1]));
            v.y = pack2(f2bf(acc[bl][2]), f2bf(acc[bl][3]));
            *(int2*)&ob[lg * 64 + wave * 16 + quad * 4] = v;
        }
    }
    if (src) {                                   // vh [D, L]
        short* ob = vh + (size_t)bhh * 64 * L + l0;
        #pragma unroll
        for (int bl = 0; bl < 4; bl++)
            #pragma unroll
            for (int r = 0; r < 4; r++)
                ob[(wave * 16 + quad * 4 + r) * L + bl * 16 + n] = f2bf(acc2[bl][r]);
    }
}

// ---------------------------------------------------------------------------
// Causal flash attention, bf16 MFMA (unchanged from round 2).
// ---------------------------------------------------------------------------
__global__ __launch_bounds__(256, 4) void flash_kernel(
    const short* __restrict__ qh, const short* __restrict__ kh,
    const short* __restrict__ vh, float* __restrict__ o)
{
    int bx = blockIdx.x;
    int bh = bx & 63;
    int qt = 15 - (bx >> 6);             // heavy tiles dispatch first
    int h  = bh & 7, b = bh >> 3;

    __shared__ short Qs[64 * LDK];       // [l][d]
    __shared__ short Ks[64 * LDK];       // [key][d]
    __shared__ short Vt[64 * LDK];       // [d][key]
    __shared__ short Ps[64 * LDK];       // [l][key], per-wave 16-row slices

    int tid  = threadIdx.x;
    int wave = tid >> 6, lane = tid & 63;
    int n    = lane & 15, quad = lane >> 4;

    const short* Qg = qh + ((size_t)bh * L + qt * 64) * 64;
    for (int i = tid; i < 512; i += 256) {
        int row = i >> 3, ch = i & 7;
        *(int4*)&Qs[row * LDK + ch * 8] = ((const int4*)Qg)[i];
    }
    __syncthreads();
    bf16x8 qa0 = *(const bf16x8*)&Qs[(wave * 16 + n) * LDK + quad * 8];
    bf16x8 qa1 = *(const bf16x8*)&Qs[(wave * 16 + n) * LDK + 32 + quad * 8];

    f32x4 O0 = {0.f,0.f,0.f,0.f}, O1 = O0, O2 = O0, O3 = O0;
    float mi[4], li[4];
    #pragma unroll
    for (int r = 0; r < 4; r++) { mi[r] = -INFINITY; li[r] = 0.f; }

    const float scale = 0.35355339059327373f;   // 1/sqrt(H)

    for (int kt = 0; kt <= qt; kt++) {
        __syncthreads();
        const short* Kg = kh + ((size_t)bh * L + kt * 64) * 64;
        const short* Vg = vh + (size_t)bh * 64 * L + kt * 64;
        for (int i = tid; i < 512; i += 256) {
            int row = i >> 3, ch = i & 7;
            *(int4*)&Ks[row * LDK + ch * 8] = ((const int4*)Kg)[i];
            *(int4*)&Vt[row * LDK + ch * 8] = *(const int4*)(Vg + row * (size_t)L + ch * 8);
        }
        __syncthreads();

        f32x4 s[4];
        #pragma unroll
        for (int bk = 0; bk < 4; bk++) {
            bf16x8 kb0 = *(const bf16x8*)&Ks[(bk * 16 + n) * LDK + quad * 8];
            bf16x8 kb1 = *(const bf16x8*)&Ks[(bk * 16 + n) * LDK + 32 + quad * 8];
            f32x4 acc = {0.f,0.f,0.f,0.f};
            acc = __builtin_amdgcn_mfma_f32_16x16x32_bf16(qa0, kb0, acc, 0, 0, 0);
            acc = __builtin_amdgcn_mfma_f32_16x16x32_bf16(qa1, kb1, acc, 0, 0, 0);
            s[bk] = acc;
        }

        #pragma unroll
        for (int bk = 0; bk < 4; bk++)
            #pragma unroll
            for (int r = 0; r < 4; r++) s[bk][r] *= scale;

        if (kt == qt) {
            #pragma unroll
            for (int bk = 0; bk < 4; bk++)
                #pragma unroll
                for (int r = 0; r < 4; r++)
                    if (bk * 16 + n > wave * 16 + quad * 4 + r)
                        s[bk][r] = -INFINITY;
        }

        float rmax[4], rsum[4], alpha[4];
        #pragma unroll
        for (int r = 0; r < 4; r++)
            rmax[r] = fmaxf(fmaxf(s[0][r], s[1][r]), fmaxf(s[2][r], s[3][r]));
        #pragma unroll
        for (int off = 1; off < 16; off <<= 1)
            #pragma unroll
            for (int r = 0; r < 4; r++)
                rmax[r] = fmaxf(rmax[r], __shfl_xor(rmax[r], off, 64));

        #pragma unroll
        for (int r = 0; r < 4; r++) {
            float mnew = fmaxf(mi[r], rmax[r]);
            alpha[r] = __expf(mi[r] - mnew);
            mi[r] = mnew;
            float ls = 0.f;
            #pragma unroll
            for (int bk = 0; bk < 4; bk++) {
                float p = __expf(s[bk][r] - mnew);
                s[bk][r] = p;
                ls += p;
            }
            rsum[r] = ls;
        }
        #pragma unroll
        for (int off = 1; off < 16; off <<= 1)
            #pragma unroll
            for (int r = 0; r < 4; r++)
                rsum[r] += __shfl_xor(rsum[r], off, 64);

        #pragma unroll
        for (int r = 0; r < 4; r++) {
            li[r] = li[r] * alpha[r] + rsum[r];
            O0[r] *= alpha[r]; O1[r] *= alpha[r];
            O2[r] *= alpha[r]; O3[r] *= alpha[r];
        }

        #pragma unroll
        for (int bk = 0; bk < 4; bk++)
            #pragma unroll
            for (int r = 0; r < 4; r++)
                Ps[(wave * 16 + quad * 4 + r) * LDK + bk * 16 + n] = f2bf(s[bk][r]);

        bf16x8 pa0 = *(const bf16x8*)&Ps[(wave * 16 + n) * LDK + quad * 8];
        bf16x8 pa1 = *(const bf16x8*)&Ps[(wave * 16 + n) * LDK + 32 + quad * 8];

        {
            bf16x8 v0, v1;
            v0 = *(const bf16x8*)&Vt[(0 * 16 + n) * LDK + quad * 8];
            v1 = *(const bf16x8*)&Vt[(0 * 16 + n) * LDK + 32 + quad * 8];
            O0 = __builtin_amdgcn_mfma_f32_16x16x32_bf16(pa0, v0, O0, 0, 0, 0);
            O0 = __builtin_amdgcn_mfma_f32_16x16x32_bf16(pa1, v1, O0, 0, 0, 0);
            v0 = *(const bf16x8*)&Vt[(1 * 16 + n) * LDK + quad * 8];
            v1 = *(const bf16x8*)&Vt[(1 * 16 + n) * LDK + 32 + quad * 8];
            O1 = __builtin_amdgcn_mfma_f32_16x16x32_bf16(pa0, v0, O1, 0, 0, 0);
            O1 = __builtin_amdgcn_mfma_f32_16x16x32_bf16(pa1, v1, O1, 0, 0, 0);
            v0 = *(const bf16x8*)&Vt[(2 * 16 + n) * LDK + quad * 8];
            v1 = *(const bf16x8*)&Vt[(2 * 16 + n) * LDK + 32 + quad * 8];
            O2 = __builtin_amdgcn_mfma_f32_16x16x32_bf16(pa0, v0, O2, 0, 0, 0);
            O2 = __builtin_amdgcn_mfma_f32_16x16x32_bf16(pa1, v1, O2, 0, 0, 0);
            v0 = *(const bf16x8*)&Vt[(3 * 16 + n) * LDK + quad * 8];
            v1 = *(const bf16x8*)&Vt[(3 * 16 + n) * LDK + 32 + quad * 8];
            O3 = __builtin_amdgcn_mfma_f32_16x16x32_bf16(pa0, v0, O3, 0, 0, 0);
            O3 = __builtin_amdgcn_mfma_f32_16x16x32_bf16(pa1, v1, O3, 0, 0, 0);
        }
    }

    #pragma unroll
    for (int r = 0; r < 4; r++) {
        float inv = 1.f / li[r];
        int lg = qt * 64 + wave * 16 + quad * 4 + r;
        float* ob = o + ((size_t)b * L + lg) * C + h * 64;
        ob[n]      = O0[r] * inv;
        ob[16 + n] = O1[r] * inv;
        ob[32 + n] = O2[r] * inv;
        ob[48 + n] = O3[r] * inv;
    }
}

// ---------------------------------------------------------------------------
// Residual + LayerNorm over channels; transposed write y[B,C,L]. (unchanged)
// ---------------------------------------------------------------------------
__global__ __launch_bounds__(256) void ln_kernel(
    const float* __restrict__ o, const float* __restrict__ q,
    const float* __restrict__ gamma, const float* __restrict__ beta,
    float* __restrict__ y)
{
    int bx = blockIdx.x;
    int tile = bx & 63;
    int b = bx >> 6;
    int l0 = tile * 16;
    int tid = threadIdx.x;

    __shared__ float xt[16 * 516];
    __shared__ float mu_s[16], rs_s[16];

    const float4* og = (const float4*)(o + ((size_t)b * L + l0) * C);
    for (int i = tid; i < 16 * 128; i += 256) {
        int l = i >> 7, c4 = i & 127;
        *(float4*)&xt[l * 516 + c4 * 4] = og[l * 128 + c4];
    }
    __syncthreads();
    const float* qb = q + (size_t)b * C * L + l0;
    for (int i = tid; i < 16 * 512; i += 256) {
        int c = i >> 4, lq = i & 15;
        xt[lq * 516 + c] += qb[c * L + lq];
    }
    __syncthreads();
    {
        int l = tid >> 4, sub = tid & 15;
        float s = 0.f, ss = 0.f;
        for (int j = 0; j < 32; j++) {
            float v = xt[l * 516 + sub + 16 * j];
            s += v; ss += v * v;
        }
        #pragma unroll
        for (int off = 1; off < 16; off <<= 1) {
            s  += __shfl_xor(s, off, 64);
            ss += __shfl_xor(ss, off, 64);
        }
        if (sub == 0) {
            float mean = s * (1.f / 512.f);
            float var  = ss * (1.f / 512.f) - mean * mean;
            mu_s[l] = mean;
            rs_s[l] = rsqrtf(var + 1e-5f);
        }
    }
    __syncthreads();
    float* yb = y + (size_t)b * C * L + l0;
    for (int i = tid; i < 16 * 512; i += 256) {
        int c = i >> 4, lq = i & 15;
        float v = (xt[lq * 516 + c] - mu_s[lq]) * rs_s[lq] * gamma[c] + beta[c];
        yb[c * L + lq] = v;
    }
}

// ---------------------------------------------------------------------------
extern "C" void kernel_launch(void* const* d_in, const int* in_sizes, int n_in,
                              void* d_out, int out_size, void* d_ws, size_t ws_size,
                              hipStream_t stream)
{
    const float* q     = (const float*)d_in[0];
    const float* k     = (const float*)d_in[1];
    // d_in[2] = mask — analytic
    const float* wq    = (const float*)d_in[3];
    const float* wk    = (const float*)d_in[4];
    const float* wv    = (const float*)d_in[5];
    const float* gamma = (const float*)d_in[6];
    const float* beta  = (const float*)d_in[7];
    float* y = (float*)d_out;

    const size_t N = (size_t)B * H * L * D;      // 4,194,304
    short* qh  = (short*)d_ws;                   // [BH, L, D] bf16
    short* kh  = qh + N;                         // [BH, L, D] bf16
    short* vh  = kh + N;                         // [BH, D, L] bf16
    float* o   = (float*)(vh + N);               // [B, L, C] fp32
    short* wtg = (short*)(o + (size_t)B * L * C);// 294912 bf16 A-frag weights

    wprep_kernel<<<1152, 256, 0, stream>>>(wq, wk, wv, wtg);
    conv_kernel<<<2 * B * H * (L / 64), 256, 0, stream>>>(q, k, wtg, qh, kh, vh);
    flash_kernel<<<B * H * (L / 64), 256, 0, stream>>>(qh, kh, vh, o);
    ln_kernel<<<B * (L / 16), 256, 0, stream>>>(o, q, gamma, beta, y);
}